// Round 5
// baseline (562.626 us; speedup 1.0000x reference)
//
#include <hip/hip_runtime.h>
#include <cstdint>
#include <cstddef>

#define NB 32
#define NP 24564
#define NC 81
#define NO 8

// ---------- workspace layout (total ~3.15 MB) ----------
// [0,   24)   double acc[3]   {ce_pos_sum, loc_sum, hard_neg_sum}
// [64,  192)  int    n_pos[NB]
// [256, 2304) u64    best_key[NB*NO]
// [2304, +NB*NP*4) float ce_neg

// ---------- helpers ----------
__device__ __forceinline__ unsigned long long wave_max_u64(unsigned long long v) {
    #pragma unroll
    for (int m = 32; m >= 1; m >>= 1) {
        unsigned long long o = __shfl_xor(v, m, 64);
        v = (o > v) ? o : v;
    }
    return v;
}

// IoU of prior (xy corners precomputed) vs box o. fp contract OFF so the
// discrete IoU<0.5 threshold matches XLA bit-for-bit.
__device__ __forceinline__ float iou_one(const float4 bx,
                                         float px1, float py1, float px2, float py2,
                                         float area_p) {
#pragma clang fp contract(off)
    float iw = fminf(bx.z, px2) - fmaxf(bx.x, px1);
    float ih = fminf(bx.w, py2) - fmaxf(bx.y, py1);
    iw = fmaxf(iw, 0.f); ih = fmaxf(ih, 0.f);
    const float inter = iw * ih;
    const float area_b = (bx.z - bx.x) * (bx.w - bx.y);
    return inter / ((area_b + area_p) - inter);
}

__device__ __forceinline__ void prior_corners(const float4 pr,
                                              float& px1, float& py1,
                                              float& px2, float& py2, float& area_p) {
#pragma clang fp contract(off)
    const float hw = pr.z / 2.0f, hh = pr.w / 2.0f;
    px1 = pr.x - hw; py1 = pr.y - hh;
    px2 = pr.x + hw; py2 = pr.y + hh;
    area_p = (px2 - px1) * (py2 - py1);
}

// ---------- kernel Z: zero the small accumulator region (graph-capture-safe init) ----------
__global__ void kZ(double* __restrict__ acc, int* __restrict__ n_pos,
                   unsigned long long* __restrict__ best_key) {
    const int t = threadIdx.x;           // 256 threads
    if (t < 3)  acc[t] = 0.0;
    if (t < NB) n_pos[t] = 0;
    best_key[t] = 0ull;                  // NB*NO == 256
}

// ---------- kernel A: per-object argmax over priors (on ORIGINAL overlaps) ----------
// key = (iou_bits << 32) | (NP-1-p): max key == max iou, tie -> smallest p
// (first occurrence, matching jnp.argmax).
__global__ __launch_bounds__(256) void kA(const float* __restrict__ boxes,
                                          const float* __restrict__ priors,
                                          unsigned long long* __restrict__ best_key) {
    const int b = blockIdx.y;
    const int p = blockIdx.x * 256 + threadIdx.x;
    const bool valid = (p < NP);

    float px1 = 0.f, py1 = 0.f, px2 = 0.f, py2 = 0.f, area_p = 0.f;
    if (valid) prior_corners(((const float4*)priors)[p], px1, py1, px2, py2, area_p);

    const float4* bx4 = ((const float4*)boxes) + b * NO;
    #pragma unroll
    for (int o = 0; o < NO; ++o) {
        unsigned long long key = 0ull;
        if (valid) {
            const float iou = iou_one(bx4[o], px1, py1, px2, py2, area_p);
            key = (((unsigned long long)__float_as_uint(iou)) << 32)
                | (unsigned)(NP - 1 - p);
        }
        const unsigned long long k = wave_max_u64(key);
        if ((threadIdx.x & 63) == 0) atomicMax(&best_key[b * NO + o], k);
    }
}

// ---------- kernel C: matching (recomputed) + CE + positives + loc loss ----------
#define TC 128
__global__ __launch_bounds__(TC) void kC(const float* __restrict__ scores,
                                         const float* __restrict__ pred_loc,
                                         const float* __restrict__ boxes,
                                         const float* __restrict__ priors,
                                         const int* __restrict__ labels,
                                         const unsigned long long* __restrict__ best_key,
                                         float* __restrict__ ce_neg,
                                         int* __restrict__ n_pos,
                                         double* __restrict__ acc) {
    __shared__ float s[TC * NC];          // 41472 B -> 3 blocks/CU
    __shared__ float red_f[2][TC / 64];
    __shared__ int   red_i[TC / 64];

    const int b  = blockIdx.y;
    const int p0 = blockIdx.x * TC;
    const int rows = min(TC, NP - p0);
    const size_t base = ((size_t)b * NP + p0) * NC;

    // float4-vectorized staging: rows*NC divisible by 4 (10368 or 9396),
    // base 16B-aligned (p0 % 128 == 0, 128*81*4 % 16 == 0).
    {
        const float4* __restrict__ src4 = (const float4*)(scores + base);
        float4* __restrict__ s4 = (float4*)s;
        const int n4 = (rows * NC) >> 2;
        for (int i = threadIdx.x; i < n4; i += TC) s4[i] = src4[i];
    }
    __syncthreads();

    float ce_pos = 0.f, locs = 0.f; int np = 0;
    if ((int)threadIdx.x < rows) {
        const int row = threadIdx.x;
        const int p = p0 + row;

        // ---- recompute matching for this prior ----
        float px1, py1, px2, py2, area_p;
        const float4 pr = ((const float4*)priors)[p];
        prior_corners(pr, px1, py1, px2, py2, area_p);
        const float4* bx4 = ((const float4*)boxes) + b * NO;
        float bov = -1.0f; int bobj = 0;
        #pragma unroll
        for (int o = 0; o < NO; ++o) {
            const float iou = iou_one(bx4[o], px1, py1, px2, py2, area_p);
            if (iou > bov) { bov = iou; bobj = o; }   // strict > : first occurrence
        }
        // forced overrides, sequential in o => "last wins" (XLA scatter order)
        #pragma unroll
        for (int o = 0; o < NO; ++o) {
            const int fp_ = NP - 1 - (int)(unsigned)(best_key[b * NO + o] & 0xffffffffu);
            if (fp_ == p) { bov = 1.0f; bobj = o; }
        }

        // ---- log-softmax CE from LDS (stride 81 ≡ 17 mod 32 → conflict-free) ----
        const float* sr = &s[row * NC];
        float m = sr[0];
        #pragma unroll
        for (int j = 1; j < NC; ++j) m = fmaxf(m, sr[j]);
        float sum = 0.f;
        #pragma unroll
        for (int j = 0; j < NC; ++j) sum += expf(sr[j] - m);
        const float lse = m + logf(sum);

        const size_t bp = (size_t)b * NP + p;
        const int label = (bov < 0.5f) ? 0 : labels[b * NO + bobj];
        const float ce = lse - sr[label];
        const bool pos = (label != 0);
        ce_neg[bp] = pos ? 0.f : ce;
        if (pos) {
            ce_pos = ce; np = 1;
            const float4 bx = bx4[bobj];
            const float cx = (bx.x + bx.z) / 2.0f, cy = (bx.y + bx.w) / 2.0f;
            const float w = bx.z - bx.x, h = bx.w - bx.y;
            const float gx = (cx - pr.x) / (pr.z / 10.0f);
            const float gy = (cy - pr.y) / (pr.w / 10.0f);
            const float gw = logf(w / pr.z) * 5.0f;
            const float gh = logf(h / pr.w) * 5.0f;
            const float4 pl = ((const float4*)pred_loc)[bp];
            locs = fabsf(pl.x - gx) + fabsf(pl.y - gy) +
                   fabsf(pl.z - gw) + fabsf(pl.w - gh);
        }
    }

    #pragma unroll
    for (int m2 = 32; m2 >= 1; m2 >>= 1) {
        ce_pos += __shfl_xor(ce_pos, m2, 64);
        locs   += __shfl_xor(locs,   m2, 64);
        np     += __shfl_xor(np,     m2, 64);
    }
    const int wid = threadIdx.x >> 6;
    if ((threadIdx.x & 63) == 0) { red_f[0][wid] = ce_pos; red_f[1][wid] = locs; red_i[wid] = np; }
    __syncthreads();
    if (threadIdx.x == 0) {
        float cp = 0.f, lc = 0.f; int n = 0;
        #pragma unroll
        for (int wv = 0; wv < TC / 64; ++wv) { cp += red_f[0][wv]; lc += red_f[1][wv]; n += red_i[wv]; }
        if (cp != 0.f) atomicAdd(&acc[0], (double)cp);
        if (lc != 0.f) atomicAdd(&acc[1], (double)lc);
        if (n)         atomicAdd(&n_pos[b], n);
    }
}

// ---------- kernel D: per-image top-K sum of ce_neg (exact, bitwise K-th-largest) ----------
#define TD 256
#define VPT 96   // ceil(NP/TD)
__global__ __launch_bounds__(TD) void kD(const float* __restrict__ ce_neg,
                                         const int* __restrict__ n_pos,
                                         double* __restrict__ acc) {
    const int b = blockIdx.x;
    const int tid = threadIdx.x;
    __shared__ int   red_i[TD / 64];
    __shared__ float red_f[TD / 64];

    unsigned v[VPT];
    const float* src = ce_neg + (size_t)b * NP;
    #pragma unroll
    for (int it = 0; it < VPT; ++it) {
        const int i = it * TD + tid;
        v[it] = (i < NP) ? __float_as_uint(src[i]) : 0u;
    }

    int K = 3 * n_pos[b];
    if (K > NP) K = NP;

    // binary-search the K-th largest value over uint bit-patterns
    // (CE >= 0, so float order == uint order)
    unsigned t = 0;
    for (int bit = 31; bit >= 0; --bit) {
        const unsigned cand = t | (1u << bit);
        int cnt = 0;
        #pragma unroll
        for (int it = 0; it < VPT; ++it) cnt += (v[it] >= cand) ? 1 : 0;
        #pragma unroll
        for (int m2 = 32; m2 >= 1; m2 >>= 1) cnt += __shfl_xor(cnt, m2, 64);
        if ((tid & 63) == 0) red_i[tid >> 6] = cnt;
        __syncthreads();
        const int total = red_i[0] + red_i[1] + red_i[2] + red_i[3];
        if (total >= K) t = cand;
        __syncthreads();
    }

    // sum of strictly-greater values + tie fill at threshold == exact top-K sum
    float ssum = 0.f; int cgt = 0;
    #pragma unroll
    for (int it = 0; it < VPT; ++it) {
        if (v[it] > t) { ssum += __uint_as_float(v[it]); ++cgt; }
    }
    #pragma unroll
    for (int m2 = 32; m2 >= 1; m2 >>= 1) {
        ssum += __shfl_xor(ssum, m2, 64);
        cgt  += __shfl_xor(cgt,  m2, 64);
    }
    if ((tid & 63) == 0) { red_f[tid >> 6] = ssum; red_i[tid >> 6] = cgt; }
    __syncthreads();
    if (tid == 0 && K > 0) {
        const float s4 = red_f[0] + red_f[1] + red_f[2] + red_f[3];
        const int   c4 = red_i[0] + red_i[1] + red_i[2] + red_i[3];
        const double hard = (double)s4 + (double)(K - c4) * (double)__uint_as_float(t);
        atomicAdd(&acc[2], hard);
    }
}

// ---------- kernel E: finalize ----------
__global__ void kE(const int* __restrict__ n_pos,
                   const double* __restrict__ acc,
                   float* __restrict__ out) {
    if (threadIdx.x == 0) {
        int npt = 0;
        #pragma unroll
        for (int b = 0; b < NB; ++b) npt += n_pos[b];
        const double n = (double)npt;
        const double conf = (acc[2] + acc[0]) / n;
        const double loc  = acc[1] / (n * 4.0);
        out[0] = (float)(conf + loc);
    }
}

// ---------- launch ----------
extern "C" void kernel_launch(void* const* d_in, const int* in_sizes, int n_in,
                              void* d_out, int out_size, void* d_ws, size_t ws_size,
                              hipStream_t stream) {
    (void)in_sizes; (void)n_in; (void)out_size; (void)ws_size;
    const float* pred_loc = (const float*)d_in[0];
    const float* scores   = (const float*)d_in[1];
    const float* boxes    = (const float*)d_in[2];
    const float* priors   = (const float*)d_in[3];
    const int*   labels   = (const int*)d_in[4];
    float* out = (float*)d_out;

    char* ws = (char*)d_ws;
    double* acc = (double*)ws;
    int* n_pos = (int*)(ws + 64);
    unsigned long long* best_key = (unsigned long long*)(ws + 256);
    float* ce_neg = (float*)(ws + 2304);

    kZ<<<1, 256, 0, stream>>>(acc, n_pos, best_key);
    dim3 gA((NP + 255) / 256, NB);
    kA<<<gA, 256, 0, stream>>>(boxes, priors, best_key);
    dim3 gC((NP + TC - 1) / TC, NB);
    kC<<<gC, TC, 0, stream>>>(scores, pred_loc, boxes, priors, labels,
                              best_key, ce_neg, n_pos, acc);
    kD<<<NB, TD, 0, stream>>>(ce_neg, n_pos, acc);
    kE<<<1, 1, 0, stream>>>(n_pos, acc, out);
}

// Round 7
// 531.861 us; speedup vs baseline: 1.0578x; 1.0578x over previous
//
#include <hip/hip_runtime.h>
#include <cstdint>
#include <cstddef>

#define NB 32
#define NP 24564
#define NC 81
#define NO 8

// ---------- workspace layout (total ~3.15 MB) ----------
// [0,   24)   double acc[3]   {ce_pos_sum, loc_sum, hard_neg_sum}
// [64,  192)  int    n_pos[NB]
// [256, 2304) u64    best_key[NB*NO]
// [2304, +NB*NP*4) float ce_neg

// ---------- helpers ----------
__device__ __forceinline__ unsigned long long wave_max_u64(unsigned long long v) {
    #pragma unroll
    for (int m = 32; m >= 1; m >>= 1) {
        unsigned long long o = __shfl_xor(v, m, 64);
        v = (o > v) ? o : v;
    }
    return v;
}

// IoU of prior (xy corners precomputed) vs box o. fp contract OFF so the
// discrete IoU<0.5 threshold matches XLA bit-for-bit (R5 validated: absmax==0).
__device__ __forceinline__ float iou_one(const float4 bx,
                                         float px1, float py1, float px2, float py2,
                                         float area_p) {
#pragma clang fp contract(off)
    float iw = fminf(bx.z, px2) - fmaxf(bx.x, px1);
    float ih = fminf(bx.w, py2) - fmaxf(bx.y, py1);
    iw = fmaxf(iw, 0.f); ih = fmaxf(ih, 0.f);
    const float inter = iw * ih;
    const float area_b = (bx.z - bx.x) * (bx.w - bx.y);
    return inter / ((area_b + area_p) - inter);
}

__device__ __forceinline__ void prior_corners(const float4 pr,
                                              float& px1, float& py1,
                                              float& px2, float& py2, float& area_p) {
#pragma clang fp contract(off)
    const float hw = pr.z / 2.0f, hh = pr.w / 2.0f;
    px1 = pr.x - hw; py1 = pr.y - hh;
    px2 = pr.x + hw; py2 = pr.y + hh;
    area_p = (px2 - px1) * (py2 - py1);
}

// ---------- kernel Z: zero the small accumulator region (graph-capture-safe init) ----------
__global__ void kZ(double* __restrict__ acc, int* __restrict__ n_pos,
                   unsigned long long* __restrict__ best_key) {
    const int t = threadIdx.x;           // 256 threads
    if (t < 3)  acc[t] = 0.0;
    if (t < NB) n_pos[t] = 0;
    best_key[t] = 0ull;                  // NB*NO == 256
}

// ---------- kernel A: per-object argmax over priors (on ORIGINAL overlaps) ----------
__global__ __launch_bounds__(256) void kA(const float* __restrict__ boxes,
                                          const float* __restrict__ priors,
                                          unsigned long long* __restrict__ best_key) {
    const int b = blockIdx.y;
    const int p = blockIdx.x * 256 + threadIdx.x;
    const bool valid = (p < NP);

    float px1 = 0.f, py1 = 0.f, px2 = 0.f, py2 = 0.f, area_p = 0.f;
    if (valid) prior_corners(((const float4*)priors)[p], px1, py1, px2, py2, area_p);

    const float4* bx4 = ((const float4*)boxes) + b * NO;
    #pragma unroll
    for (int o = 0; o < NO; ++o) {
        unsigned long long key = 0ull;
        if (valid) {
            const float iou = iou_one(bx4[o], px1, py1, px2, py2, area_p);
            key = (((unsigned long long)__float_as_uint(iou)) << 32)
                | (unsigned)(NP - 1 - p);
        }
        const unsigned long long k = wave_max_u64(key);
        if ((threadIdx.x & 63) == 0) atomicMax(&best_key[b * NO + o], k);
    }
}

// ---------- kernel C: matching (recomputed) + CE + positives + loc loss ----------
// R5: latency-bound (706 GB/s, VALUBusy 19%) — runtime-trip-count staging loop
// serialized load->waitcnt->ds_write. R6: global_load_lds with divergent LDS
// operand broke correctness (must be wave-uniform base, m104). R7 fix: deep
// register staging — 20 unrolled loads into regs, then 20 ds_writes; all loads
// issue back-to-back, counted vmcnt drains amortize one HBM latency over 20.
#define TC 128
#define FULL4 ((TC * NC) / 4)   // 2592 float4 per full tile
#define VPTC (FULL4 / TC)       // 20 per thread, + 32-thread tail
__global__ __launch_bounds__(TC) void kC(const float* __restrict__ scores,
                                         const float* __restrict__ pred_loc,
                                         const float* __restrict__ boxes,
                                         const float* __restrict__ priors,
                                         const int* __restrict__ labels,
                                         const unsigned long long* __restrict__ best_key,
                                         float* __restrict__ ce_neg,
                                         int* __restrict__ n_pos,
                                         double* __restrict__ acc) {
    __shared__ float s[TC * NC];          // 41472 B -> 3 blocks/CU (LDS-capped)
    __shared__ float red_f[2][TC / 64];
    __shared__ int   red_i[TC / 64];

    const int b  = blockIdx.y;
    const int p0 = blockIdx.x * TC;
    const int rows = min(TC, NP - p0);
    const size_t base = ((size_t)b * NP + p0) * NC;

    if (rows == TC) {
        // Full tile: issue all 20 (+tail) loads first, then write to LDS.
        const float4* __restrict__ src4 = (const float4*)(scores + base);
        float4* __restrict__ s4 = (float4*)s;
        float4 r[VPTC];
        #pragma unroll
        for (int i = 0; i < VPTC; ++i) r[i] = src4[threadIdx.x + i * TC];
        float4 rt;
        const bool tail = (threadIdx.x < (FULL4 - VPTC * TC));   // 32 threads
        if (tail) rt = src4[VPTC * TC + threadIdx.x];
        #pragma unroll
        for (int i = 0; i < VPTC; ++i) s4[threadIdx.x + i * TC] = r[i];
        if (tail) s4[VPTC * TC + threadIdx.x] = rt;
    } else {
        // Tail tile (116 rows, one block per image): synchronous fallback.
        const float4* __restrict__ src4 = (const float4*)(scores + base);
        float4* __restrict__ s4 = (float4*)s;
        const int n4 = (rows * NC) >> 2;
        for (int i = threadIdx.x; i < n4; i += TC) s4[i] = src4[i];
    }
    __syncthreads();

    float ce_pos = 0.f, locs = 0.f; int np = 0;
    if ((int)threadIdx.x < rows) {
        const int row = threadIdx.x;
        const int p = p0 + row;

        // ---- recompute matching for this prior ----
        float px1, py1, px2, py2, area_p;
        const float4 pr = ((const float4*)priors)[p];
        prior_corners(pr, px1, py1, px2, py2, area_p);
        const float4* bx4 = ((const float4*)boxes) + b * NO;
        float bov = -1.0f; int bobj = 0;
        #pragma unroll
        for (int o = 0; o < NO; ++o) {
            const float iou = iou_one(bx4[o], px1, py1, px2, py2, area_p);
            if (iou > bov) { bov = iou; bobj = o; }   // strict > : first occurrence
        }
        // forced overrides, sequential in o => "last wins" (XLA scatter order)
        #pragma unroll
        for (int o = 0; o < NO; ++o) {
            const int fp_ = NP - 1 - (int)(unsigned)(best_key[b * NO + o] & 0xffffffffu);
            if (fp_ == p) { bov = 1.0f; bobj = o; }
        }

        // ---- log-softmax CE from LDS (stride 81 ≡ 17 mod 32 → conflict-free) ----
        const float* sr = &s[row * NC];
        float m = sr[0];
        #pragma unroll
        for (int j = 1; j < NC; ++j) m = fmaxf(m, sr[j]);
        float sum = 0.f;
        #pragma unroll
        for (int j = 0; j < NC; ++j) sum += expf(sr[j] - m);
        const float lse = m + logf(sum);

        const size_t bp = (size_t)b * NP + p;
        const int label = (bov < 0.5f) ? 0 : labels[b * NO + bobj];
        const float ce = lse - sr[label];
        const bool pos = (label != 0);
        ce_neg[bp] = pos ? 0.f : ce;
        if (pos) {
            ce_pos = ce; np = 1;
            const float4 bx = bx4[bobj];
            const float cx = (bx.x + bx.z) / 2.0f, cy = (bx.y + bx.w) / 2.0f;
            const float w = bx.z - bx.x, h = bx.w - bx.y;
            const float gx = (cx - pr.x) / (pr.z / 10.0f);
            const float gy = (cy - pr.y) / (pr.w / 10.0f);
            const float gw = logf(w / pr.z) * 5.0f;
            const float gh = logf(h / pr.w) * 5.0f;
            const float4 pl = ((const float4*)pred_loc)[bp];
            locs = fabsf(pl.x - gx) + fabsf(pl.y - gy) +
                   fabsf(pl.z - gw) + fabsf(pl.w - gh);
        }
    }

    #pragma unroll
    for (int m2 = 32; m2 >= 1; m2 >>= 1) {
        ce_pos += __shfl_xor(ce_pos, m2, 64);
        locs   += __shfl_xor(locs,   m2, 64);
        np     += __shfl_xor(np,     m2, 64);
    }
    const int wid = threadIdx.x >> 6;
    if ((threadIdx.x & 63) == 0) { red_f[0][wid] = ce_pos; red_f[1][wid] = locs; red_i[wid] = np; }
    __syncthreads();
    if (threadIdx.x == 0) {
        float cp = 0.f, lc = 0.f; int n = 0;
        #pragma unroll
        for (int wv2 = 0; wv2 < TC / 64; ++wv2) { cp += red_f[0][wv2]; lc += red_f[1][wv2]; n += red_i[wv2]; }
        if (cp != 0.f) atomicAdd(&acc[0], (double)cp);
        if (lc != 0.f) atomicAdd(&acc[1], (double)lc);
        if (n)         atomicAdd(&n_pos[b], n);
    }
}

// ---------- kernel D: per-image top-K sum of ce_neg (exact, bitwise K-th-largest) ----------
#define TD 256
#define VPT 96   // ceil(NP/TD)
__global__ __launch_bounds__(TD) void kD(const float* __restrict__ ce_neg,
                                         const int* __restrict__ n_pos,
                                         double* __restrict__ acc) {
    const int b = blockIdx.x;
    const int tid = threadIdx.x;
    __shared__ int   red_i[TD / 64];
    __shared__ float red_f[TD / 64];

    unsigned v[VPT];
    const float* src = ce_neg + (size_t)b * NP;
    #pragma unroll
    for (int it = 0; it < VPT; ++it) {
        const int i = it * TD + tid;
        v[it] = (i < NP) ? __float_as_uint(src[i]) : 0u;
    }

    int K = 3 * n_pos[b];
    if (K > NP) K = NP;

    // binary-search the K-th largest value over uint bit-patterns
    // (CE >= 0, so float order == uint order)
    unsigned t = 0;
    for (int bit = 31; bit >= 0; --bit) {
        const unsigned cand = t | (1u << bit);
        int cnt = 0;
        #pragma unroll
        for (int it = 0; it < VPT; ++it) cnt += (v[it] >= cand) ? 1 : 0;
        #pragma unroll
        for (int m2 = 32; m2 >= 1; m2 >>= 1) cnt += __shfl_xor(cnt, m2, 64);
        if ((tid & 63) == 0) red_i[tid >> 6] = cnt;
        __syncthreads();
        const int total = red_i[0] + red_i[1] + red_i[2] + red_i[3];
        if (total >= K) t = cand;
        __syncthreads();
    }

    // sum of strictly-greater values + tie fill at threshold == exact top-K sum
    float ssum = 0.f; int cgt = 0;
    #pragma unroll
    for (int it = 0; it < VPT; ++it) {
        if (v[it] > t) { ssum += __uint_as_float(v[it]); ++cgt; }
    }
    #pragma unroll
    for (int m2 = 32; m2 >= 1; m2 >>= 1) {
        ssum += __shfl_xor(ssum, m2, 64);
        cgt  += __shfl_xor(cgt,  m2, 64);
    }
    if ((tid & 63) == 0) { red_f[tid >> 6] = ssum; red_i[tid >> 6] = cgt; }
    __syncthreads();
    if (tid == 0 && K > 0) {
        const float s4 = red_f[0] + red_f[1] + red_f[2] + red_f[3];
        const int   c4 = red_i[0] + red_i[1] + red_i[2] + red_i[3];
        const double hard = (double)s4 + (double)(K - c4) * (double)__uint_as_float(t);
        atomicAdd(&acc[2], hard);
    }
}

// ---------- kernel E: finalize ----------
__global__ void kE(const int* __restrict__ n_pos,
                   const double* __restrict__ acc,
                   float* __restrict__ out) {
    if (threadIdx.x == 0) {
        int npt = 0;
        #pragma unroll
        for (int b = 0; b < NB; ++b) npt += n_pos[b];
        const double n = (double)npt;
        const double conf = (acc[2] + acc[0]) / n;
        const double loc  = acc[1] / (n * 4.0);
        out[0] = (float)(conf + loc);
    }
}

// ---------- launch ----------
extern "C" void kernel_launch(void* const* d_in, const int* in_sizes, int n_in,
                              void* d_out, int out_size, void* d_ws, size_t ws_size,
                              hipStream_t stream) {
    (void)in_sizes; (void)n_in; (void)out_size; (void)ws_size;
    const float* pred_loc = (const float*)d_in[0];
    const float* scores   = (const float*)d_in[1];
    const float* boxes    = (const float*)d_in[2];
    const float* priors   = (const float*)d_in[3];
    const int*   labels   = (const int*)d_in[4];
    float* out = (float*)d_out;

    char* ws = (char*)d_ws;
    double* acc = (double*)ws;
    int* n_pos = (int*)(ws + 64);
    unsigned long long* best_key = (unsigned long long*)(ws + 256);
    float* ce_neg = (float*)(ws + 2304);

    kZ<<<1, 256, 0, stream>>>(acc, n_pos, best_key);
    dim3 gA((NP + 255) / 256, NB);
    kA<<<gA, 256, 0, stream>>>(boxes, priors, best_key);
    dim3 gC((NP + TC - 1) / TC, NB);
    kC<<<gC, TC, 0, stream>>>(scores, pred_loc, boxes, priors, labels,
                              best_key, ce_neg, n_pos, acc);
    kD<<<NB, TD, 0, stream>>>(ce_neg, n_pos, acc);
    kE<<<1, 1, 0, stream>>>(n_pos, acc, out);
}